// Round 1
// baseline (768.126 us; speedup 1.0000x reference)
//
#include <hip/hip_runtime.h>

#define CDIV(a,b) (((a)+(b)-1)/(b))

// ---------------- histogram of dst (in-degree, without self loop) ----------------
__global__ void k_hist(const int* __restrict__ dst, int E, int* __restrict__ hist) {
    int e = blockIdx.x * 256 + threadIdx.x;
    if (e < E) atomicAdd(&hist[dst[e]], 1);
}

// ---------------- 2-level exclusive scan (tiles of 256) ----------------
__global__ void k_scan_tile(const int* __restrict__ in, int N,
                            int* __restrict__ out, int* __restrict__ tilesums) {
    __shared__ int sm[256];
    int t = threadIdx.x;
    int g = blockIdx.x * 256 + t;
    int v = (g < N) ? in[g] : 0;
    sm[t] = v;
    __syncthreads();
    for (int off = 1; off < 256; off <<= 1) {
        int x = sm[t];
        int y = (t >= off) ? sm[t - off] : 0;
        __syncthreads();
        sm[t] = x + y;
        __syncthreads();
    }
    int incl = sm[t];
    if (g < N) out[g] = incl - v;           // exclusive within tile
    if (t == 255) tilesums[blockIdx.x] = incl;
}

__global__ void k_scan_sums(int* __restrict__ sums, int B) {
    __shared__ int sm[512];
    int t = threadIdx.x;
    int v = (t < B) ? sums[t] : 0;
    sm[t] = v;
    __syncthreads();
    for (int off = 1; off < 512; off <<= 1) {
        int x = sm[t];
        int y = (t >= off) ? sm[t - off] : 0;
        __syncthreads();
        sm[t] = x + y;
        __syncthreads();
    }
    if (t < B) sums[t] = sm[t] - v;         // exclusive tile offsets
}

__global__ void k_scan_add(int* __restrict__ rowst, int N,
                           const int* __restrict__ sums, int* __restrict__ cursor) {
    int g = blockIdx.x * 256 + threadIdx.x;
    if (g < N) {
        int v = rowst[g] + sums[blockIdx.x];
        rowst[g] = v;
        cursor[g] = v;
    }
}

// ---------------- per-node: inv_sqrt(deg) and xi = x*inv ----------------
__global__ void k_inv(const int* __restrict__ hist, const float* __restrict__ x, int N,
                      float* __restrict__ inv, float* __restrict__ xi) {
    int i = blockIdx.x * 256 + threadIdx.x;
    if (i < N) {
        float iv = rsqrtf((float)(hist[i] + 1));   // +1 self loop
        inv[i] = iv;
        xi[i]  = x[i] * iv;
    }
}

// ---------------- scatter edges into CSR buckets ----------------
__global__ void k_scatter(const int* __restrict__ src, const int* __restrict__ dst, int E,
                          int* __restrict__ cursor, int* __restrict__ sorted) {
    int e = blockIdx.x * 256 + threadIdx.x;
    if (e < E) {
        int p = atomicAdd(&cursor[dst[e]], 1);
        sorted[p] = src[e];
    }
}

// ---------------- layer-1 scalar aggregation: s[d] = inv[d]*(sum xi[src] + xi[d]) ----------------
__global__ void k_s(const int* __restrict__ sorted, const int* __restrict__ rowst,
                    const int* __restrict__ cnt, const float* __restrict__ xi,
                    const float* __restrict__ inv, int N, float* __restrict__ s) {
    int i = blockIdx.x * 256 + threadIdx.x;
    if (i < N) {
        int st = rowst[i], en = st + cnt[i];
        float acc = xi[i];                    // self-loop term
        for (int e = st; e < en; ++e) acc += xi[sorted[e]];
        s[i] = inv[i] * acc;
    }
}

// ---------------- layer-2 aggregation (pull, CSR): agg2[d,j] ----------------
// agg2[d,j] = inv[d]*( sum_{e->d} inv[src]*relu(s[src]*W1[j]+b1[j]) + inv[d]*relu(s[d]*W1[j]+b1[j]) )
__global__ __launch_bounds__(256) void k_agg2(
        const int* __restrict__ sorted, const int* __restrict__ rowst,
        const int* __restrict__ cnt, const float* __restrict__ s,
        const float* __restrict__ inv, const float* __restrict__ W1,
        const float* __restrict__ b1, int N, float* __restrict__ agg2) {
    int j   = threadIdx.x & 127;
    int grp = threadIdx.x >> 7;               // 2 groups of 128 per block
    float w  = W1[j];
    float bb = b1[j];
    int stride = gridDim.x * 2;
    for (int d = blockIdx.x * 2 + grp; d < N; d += stride) {
        int st = rowst[d], en = st + cnt[d];
        float acc = 0.f;
        for (int e = st; e < en; ++e) {
            int sN = sorted[e];                          // broadcast load
            float o = fmaxf(fmaf(s[sN], w, bb), 0.f);    // out1[src,j] on the fly
            acc = fmaf(inv[sN], o, acc);
        }
        float oself = fmaxf(fmaf(s[d], w, bb), 0.f);
        agg2[d * 128 + j] = inv[d] * (acc + inv[d] * oself);
    }
}

// ---------------- matmul + bias + relu + global-add-pool ----------------
// pool[j] += sum_d relu( agg2[d,:] @ W2[:,j] + b2[j] )
__global__ __launch_bounds__(256) void k_mm_pool(
        const float* __restrict__ agg2, const float* __restrict__ W2,
        const float* __restrict__ b2, int N, float* __restrict__ pool) {
    __shared__ float sW[128 * 128];   // 64 KB
    __shared__ float sA[32 * 128];    // 16 KB
    int t = threadIdx.x;
    for (int i = t; i < 128 * 128; i += 256) sW[i] = W2[i];
    int j   = t & 127;
    int grp = t >> 7;
    float bb = b2[j];
    float poolAcc = 0.f;
    for (int base = blockIdx.x * 32; base < N; base += gridDim.x * 32) {
        __syncthreads();                       // previous tile fully consumed (and sW ready, iter 0)
        int nn  = N - base; if (nn > 32) nn = 32;
        int lim = nn * 128;
        for (int i = t; i < 32 * 128; i += 256)
            sA[i] = (i < lim) ? agg2[base * 128 + i] : 0.f;
        __syncthreads();
        int d0 = grp * 16;
        for (int q = 0; q < 16; q += 8) {
            float a0 = bb, a1 = bb, a2 = bb, a3 = bb, a4 = bb, a5 = bb, a6 = bb, a7 = bb;
            const float* r = &sA[(d0 + q) * 128];
            for (int k = 0; k < 128; ++k) {
                float wv = sW[k * 128 + j];    // 2-way LDS alias: free
                a0 = fmaf(r[k          ], wv, a0);
                a1 = fmaf(r[k + 128    ], wv, a1);
                a2 = fmaf(r[k + 256    ], wv, a2);
                a3 = fmaf(r[k + 384    ], wv, a3);
                a4 = fmaf(r[k + 512    ], wv, a4);
                a5 = fmaf(r[k + 640    ], wv, a5);
                a6 = fmaf(r[k + 768    ], wv, a6);
                a7 = fmaf(r[k + 896    ], wv, a7);
            }
            int dn = base + d0 + q;
            if (dn + 0 < N) poolAcc += fmaxf(a0, 0.f);
            if (dn + 1 < N) poolAcc += fmaxf(a1, 0.f);
            if (dn + 2 < N) poolAcc += fmaxf(a2, 0.f);
            if (dn + 3 < N) poolAcc += fmaxf(a3, 0.f);
            if (dn + 4 < N) poolAcc += fmaxf(a4, 0.f);
            if (dn + 5 < N) poolAcc += fmaxf(a5, 0.f);
            if (dn + 6 < N) poolAcc += fmaxf(a6, 0.f);
            if (dn + 7 < N) poolAcc += fmaxf(a7, 0.f);
        }
    }
    __syncthreads();
    sA[t] = poolAcc;
    __syncthreads();
    if (t < 128) atomicAdd(&pool[j], sA[t] + sA[t + 128]);
}

// ---------------- final 257-dim dot ----------------
__global__ void k_final(const float* __restrict__ pool, const float* __restrict__ phys,
                        const float* __restrict__ Wfc, const float* __restrict__ bfc,
                        float* __restrict__ out) {
    __shared__ float sm[256];
    int t = threadIdx.x;
    float acc = pool[t] * Wfc[t];
    if (t == 0) acc += phys[0] * Wfc[256] + bfc[0];
    sm[t] = acc;
    __syncthreads();
    for (int off = 128; off > 0; off >>= 1) {
        if (t < off) sm[t] += sm[t + off];
        __syncthreads();
    }
    if (t == 0) out[0] = sm[0];
}

extern "C" void kernel_launch(void* const* d_in, const int* in_sizes, int n_in,
                              void* d_out, int out_size, void* d_ws, size_t ws_size,
                              hipStream_t stream) {
    const float* mol_x  = (const float*)d_in[0];
    const int*   mol_e  = (const int*)  d_in[1];
    const float* prot_x = (const float*)d_in[2];
    const int*   prot_e = (const int*)  d_in[3];
    const float* phys   = (const float*)d_in[4];
    const float* W1     = (const float*)d_in[5];
    const float* b1     = (const float*)d_in[6];
    const float* W2     = (const float*)d_in[7];
    const float* b2     = (const float*)d_in[8];
    const float* Wfc    = (const float*)d_in[9];
    const float* bfc    = (const float*)d_in[10];
    float* out = (float*)d_out;

    int Nm = in_sizes[0], Em = in_sizes[1] / 2;
    int Np = in_sizes[2], Ep = in_sizes[3] / 2;
    int maxN = (Nm > Np) ? Nm : Np;
    int maxE = (Em > Ep) ? Em : Ep;

    char* p = (char*)d_ws;
    auto alloc = [&](size_t bytes) -> char* {
        char* r = p;
        p += (bytes + 255) & ~(size_t)255;
        return r;
    };
    float* agg2     = (float*)alloc((size_t)maxN * 128 * 4);
    int*   sorted   = (int*)  alloc((size_t)maxE * 4);
    int*   hist     = (int*)  alloc((size_t)maxN * 4);
    int*   rowst    = (int*)  alloc((size_t)maxN * 4);
    int*   cursor   = (int*)  alloc((size_t)maxN * 4);
    int*   tilesums = (int*)  alloc(1024 * 4);
    float* inv      = (float*)alloc((size_t)maxN * 4);
    float* s        = (float*)alloc((size_t)maxN * 4);
    float* xi       = (float*)alloc((size_t)maxN * 4);
    float* pool     = (float*)alloc(256 * 4);

    hipMemsetAsync(pool, 0, 256 * 4, stream);

    auto branch = [&](const float* x, const int* edge, int N, int E, float* poolOut) {
        const int* srcp = edge;
        const int* dstp = edge + E;
        hipMemsetAsync(hist, 0, (size_t)N * 4, stream);
        k_hist<<<CDIV(E, 256), 256, 0, stream>>>(dstp, E, hist);
        int B = CDIV(N, 256);
        k_scan_tile<<<B, 256, 0, stream>>>(hist, N, rowst, tilesums);
        k_scan_sums<<<1, 512, 0, stream>>>(tilesums, B);
        k_scan_add<<<B, 256, 0, stream>>>(rowst, N, tilesums, cursor);
        k_inv<<<CDIV(N, 256), 256, 0, stream>>>(hist, x, N, inv, xi);
        k_scatter<<<CDIV(E, 256), 256, 0, stream>>>(srcp, dstp, E, cursor, sorted);
        k_s<<<CDIV(N, 256), 256, 0, stream>>>(sorted, rowst, hist, xi, inv, N, s);
        k_agg2<<<4096, 256, 0, stream>>>(sorted, rowst, hist, s, inv, W1, b1, N, agg2);
        k_mm_pool<<<512, 256, 0, stream>>>(agg2, W2, b2, N, poolOut);
    };
    branch(mol_x,  mol_e,  Nm, Em, pool);
    branch(prot_x, prot_e, Np, Ep, pool + 128);

    k_final<<<1, 256, 0, stream>>>(pool, phys, Wfc, bfc, out);
}